// Round 9
// baseline (5596.037 us; speedup 1.0000x reference)
//
#include <hip/hip_runtime.h>
#include <hip/hip_fp16.h>
#include <stdint.h>

#define Kn 64
#define En 256
#define Bn 512
#define Hn 512
#define Dn 128
#define NBLK 64      // 8 cliques x 8 slice-blocks; each block serves 4 groups (chains)
#define NTH  256
#define DT_C 0.05f

// ws layout (bytes):
//   0        pos   int[Kn*Bn]           (128 KB)
//   131072   acc   float[2]
//   196608   flg   int[32*8*32]         (32 KB: [group][slice] flag, 128B stride)
//   1048576  Hf16  __half[512][512]     (512 KB)
//   1572864  Tf16  __half[512][512]     (512 KB)
//   4194304  WF    frag-swizzled f16 weights (4.33 MB)
// WF half-offsets: W1 0, W2 262144, Wp1 524288, Wp2 786432, Wg 851968 (+g*327680)
//   frag layout per matrix: idx = ((coltile*KT + ktile)*64 + lane)*8 + e
//   element = W[ktile*32 + (lane>>4)*8 + e][coltile*16 + (lane&15)]

typedef _Float16 f16x8 __attribute__((ext_vector_type(8)));
typedef float    f32x4 __attribute__((ext_vector_type(4)));
typedef unsigned long long u64;

__device__ __forceinline__ float sigm(float x){ return 1.0f/(1.0f + __expf(-x)); }

__device__ __forceinline__ u64 ald(const u64* p){
  return __hip_atomic_load(p, __ATOMIC_RELAXED, __HIP_MEMORY_SCOPE_AGENT);
}
__device__ __forceinline__ void ash(__half* p, float v){
  __hip_atomic_store((unsigned short*)p, __half_as_ushort(__float2half(v)),
                     __ATOMIC_RELAXED, __HIP_MEMORY_SCOPE_AGENT);
}

union HU { __half h[8]; u64 q[2]; };

__global__ void k_init(int* __restrict__ pos, float* __restrict__ acc,
                       int* __restrict__ flg, uint32_t* __restrict__ hf){
  int i = blockIdx.x*blockDim.x + threadIdx.x;
  if (i < Kn*Bn) pos[i] = -1;
  if (i < 2) acc[i] = 0.0f;
  if (i < 32*8*32) flg[i] = 0;
  if (i < Hn*Hn/2) hf[i] = 0;
}

__global__ void k_scatter(const int* __restrict__ bidx, int* __restrict__ pos){
  int i = blockIdx.x*blockDim.x + threadIdx.x;
  if (i < Kn*En){
    int k = i >> 8;
    int e = i & (En-1);
    pos[(k << 9) | bidx[i]] = e;
  }
}

// frag-swizzle convert: dst layout documented above. N = src col count.
__global__ void k_cvt_frag(const float* __restrict__ src, __half* __restrict__ dst,
                           int KT, int N, int n){
  int i = blockIdx.x*blockDim.x + threadIdx.x;
  if (i >= n) return;
  int C = i / (KT*512);
  int r = i % (KT*512);
  int T = r >> 9;
  int q = r & 511;
  int l = q >> 3, e = q & 7;
  int srow = T*32 + ((l>>4)<<3) + e;
  int scol = C*16 + (l&15);
  dst[i] = __float2half(src[(size_t)srow*N + scol]);
}

__global__ __launch_bounds__(NTH, 1) void k_main(
  const float* __restrict__ X, const float* __restrict__ Mm,
  const int* __restrict__ pos, const __half* __restrict__ WF,
  __half* __restrict__ Hf, __half* __restrict__ Tf,
  const float* __restrict__ bi_, const float* __restrict__ bf_,
  const float* __restrict__ bo_, const float* __restrict__ bc_,
  const float* __restrict__ b1_, const float* __restrict__ b2_,
  const float* __restrict__ bp1_, const float* __restrict__ bp2_,
  float* __restrict__ acc, int* __restrict__ flg)
{
  const __half* W1F  = WF;
  const __half* W2F  = WF + 262144;
  const __half* Wp1F = WF + 524288;
  const __half* Wp2F = WF + 786432;
  const __half* WgF  = WF + 851968;

  const int t    = threadIdx.x;
  const int bid  = blockIdx.x;
  const int s    = bid & 7;      // slice = XCD under round-robin (perf-only)
  const int qg   = bid >> 3;     // clique 0..7; serves groups qg*4 .. qg*4+3
  const int w    = t >> 6;       // wave 0..3
  const int lane = t & 63;
  const int cl   = lane & 15;    // col within 16-col tile
  const int rq   = lane >> 4;    // row quad (samples rq*4..+3)
  const int jc   = s*64 + w*16 + cl;  // owned h-col
  const int q4   = t & 15, lrow = t >> 4;   // loss-phase ownership

  __shared__ __align__(16) __half Af[4][8192];   // 64KB: per-chain A frags (16 ktiles)
  __shared__ __align__(16) __half Xf[4][2048];   // 16KB: per-chain X frags (4 ktiles)
  __shared__ __align__(16) float  outb[1024];    // 4KB: P2 cross-wave reduce
  __shared__ float redbuf[8];

  // hoisted weights (slice coltile s*4+w)
  f16x8 W1r[16], W2r[16], wp2r[4];
  {
    const size_t cb = (size_t)(s*4 + w)*16*512 + (size_t)lane*8;
    #pragma unroll
    for (int kt=0; kt<16; kt++){
      W1r[kt] = *(const f16x8*)(W1F + cb + kt*512);
      W2r[kt] = *(const f16x8*)(W2F + cb + kt*512);
    }
    #pragma unroll
    for (int j=0;j<4;j++)
      wp2r[j] = *(const f16x8*)(Wp2F + (size_t)(s*16 + w*4 + j)*512 + (size_t)lane*8);
  }

  float Hreg[4][4], Creg[4][4];     // [chain][r], sample rq*4+r, col jc
  #pragma unroll
  for (int c=0;c<4;c++)
    #pragma unroll
    for (int r=0;r<4;r++){ Hreg[c][r]=0.f; Creg[c][r]=0.f; }

  const float vb1=b1_[jc], vb2=b2_[jc], vbp1=bp1_[jc];
  const float vbi=bi_[jc], vbf=bf_[jc], vbo=bo_[jc], vbc=bc_[jc];
  const float vbp2 = bp2_[s*16 + q4];

  f32x4 gacc[4][4];                 // [chain][gate], lives phase4 -> phase5
  float loss_loc=0.f, m_loc=0.f;
  int rnd = 0;

#define POLLW() do{                                                          \
    if (t < 32){                                                             \
      int* fp = flg + ((qg*4 + (t>>3))*8 + (t&7))*32;                        \
      while (__hip_atomic_load(fp, __ATOMIC_RELAXED,                         \
                               __HIP_MEMORY_SCOPE_AGENT) < rnd)              \
        __builtin_amdgcn_s_sleep(1);                                         \
    }                                                                        \
    __syncthreads();                                                         \
  }while(0)

#define PUBLISHW() do{                                                       \
    asm volatile("s_waitcnt vmcnt(0)" ::: "memory");                         \
    __syncthreads();                                                         \
    if (t < 4)                                                               \
      __hip_atomic_store(flg + ((qg*4 + t)*8 + s)*32, rnd+1,                 \
                         __ATOMIC_RELAXED, __HIP_MEMORY_SCOPE_AGENT);        \
    rnd++;                                                                   \
  }while(0)

#define STAGE_ALL(SRC) do{                                                   \
    const int ar = t & 15, ch = t >> 4;                                      \
    _Pragma("unroll")                                                        \
    for (int c=0;c<4;c++){                                                   \
      const u64* sp = (const u64*)((SRC) +                                   \
          ((size_t)((qg*4+c)*16 + ar))*512 + ch*32);                         \
      u64 v[8];                                                              \
      _Pragma("unroll")                                                      \
      for (int i=0;i<8;i++) v[i] = ald(sp+i);                                \
      _Pragma("unroll")                                                      \
      for (int kg=0;kg<4;kg++){                                              \
        u64* d = (u64*)(&Af[c][ch*512 + (ar+16*kg)*8]);                      \
        d[0] = v[2*kg]; d[1] = v[2*kg+1];                                    \
      }                                                                      \
    }                                                                        \
  }while(0)

  for (int k=0; k<Kn; k++){
    // ================= phases 0..3: Euler (reg weights) =================
    #pragma unroll 1
    for (int ph=0; ph<4; ph++){
      POLLW();
      const __half* srcb = (ph & 1) ? Tf : Hf;
      STAGE_ALL(srcb);
      __syncthreads();
      f32x4 a4[4];
      #pragma unroll
      for (int c=0;c<4;c++) a4[c] = (f32x4){0.f,0.f,0.f,0.f};
      if (!(ph & 1)){
        #pragma unroll
        for (int kt=0; kt<16; kt++)
          #pragma unroll
          for (int c=0;c<4;c++){
            f16x8 a = *(const f16x8*)(&Af[c][kt*512 + lane*8]);
            a4[c] = __builtin_amdgcn_mfma_f32_16x16x32_f16(a, W1r[kt], a4[c], 0,0,0);
          }
        #pragma unroll
        for (int c=0;c<4;c++)
          #pragma unroll
          for (int r=0;r<4;r++){
            const size_t grow = (size_t)((qg*4+c)*16 + rq*4 + r);
            ash(Tf + grow*512 + jc, tanhf(a4[c][r] + vb1));
          }
      } else {
        #pragma unroll
        for (int kt=0; kt<16; kt++)
          #pragma unroll
          for (int c=0;c<4;c++){
            f16x8 a = *(const f16x8*)(&Af[c][kt*512 + lane*8]);
            a4[c] = __builtin_amdgcn_mfma_f32_16x16x32_f16(a, W2r[kt], a4[c], 0,0,0);
          }
        #pragma unroll
        for (int c=0;c<4;c++)
          #pragma unroll
          for (int r=0;r<4;r++){
            Hreg[c][r] += DT_C*(a4[c][r] + vb2);
            const size_t grow = (size_t)((qg*4+c)*16 + rq*4 + r);
            ash(Hf + grow*512 + jc, Hreg[c][r]);
          }
      }
      PUBLISHW();
    }

    // ============ phase 4: P1 (publish early) + gate dots (shadow) ============
    {
      POLLW();
      STAGE_ALL(Hf);
      {  // X staging: wave w stages chain w
        const int ar = lane & 15, ch = lane >> 4;
        const int e = pos[(k<<9) + (qg*4 + w)*16 + ar];
        float xv[32];
        if (e >= 0){
          const float4* xp = (const float4*)(X + ((size_t)(k*En+e))*Dn + ch*32);
          #pragma unroll
          for (int i=0;i<8;i++){
            float4 f = xp[i];
            xv[4*i]=f.x; xv[4*i+1]=f.y; xv[4*i+2]=f.z; xv[4*i+3]=f.w;
          }
        } else {
          #pragma unroll
          for (int i=0;i<32;i++) xv[i]=0.f;
        }
        #pragma unroll
        for (int kg=0;kg<4;kg++){
          HU u;
          #pragma unroll
          for (int e8=0;e8<8;e8++) u.h[e8] = __float2half(xv[kg*8+e8]);
          u64* d = (u64*)(&Xf[w][ch*512 + (ar+16*kg)*8]);
          d[0] = u.q[0]; d[1] = u.q[1];
        }
      }
      __syncthreads();
      // P1, streamed Wp1 tiles reused across chains
      f32x4 p1[4];
      #pragma unroll
      for (int c=0;c<4;c++) p1[c] = (f32x4){0.f,0.f,0.f,0.f};
      #pragma unroll
      for (int half=0; half<2; half++){
        f16x8 wp1h[8];
        #pragma unroll
        for (int j=0;j<8;j++)
          wp1h[j] = *(const f16x8*)(Wp1F +
              (size_t)((s*4+w)*16 + half*8 + j)*512 + (size_t)lane*8);
        #pragma unroll
        for (int j=0;j<8;j++){
          const int kt = half*8 + j;
          #pragma unroll
          for (int c=0;c<4;c++){
            f16x8 a = *(const f16x8*)(&Af[c][kt*512 + lane*8]);
            p1[c] = __builtin_amdgcn_mfma_f32_16x16x32_f16(a, wp1h[j], p1[c], 0,0,0);
          }
        }
      }
      #pragma unroll
      for (int c=0;c<4;c++)
        #pragma unroll
        for (int r=0;r<4;r++){
          const size_t grow = (size_t)((qg*4+c)*16 + rq*4 + r);
          ash(Tf + grow*512 + jc, fmaxf(p1[c][r] + vbp1, 0.f));
        }
      PUBLISHW();                 // peers can start P2 staging; gates run in shadow
      if (k < Kn-1){
        #pragma unroll
        for (int g4=0; g4<4; g4++){
          #pragma unroll
          for (int c=0;c<4;c++) gacc[c][g4] = (f32x4){0.f,0.f,0.f,0.f};
          #pragma unroll
          for (int half=0; half<2; half++){
            f16x8 gw[10];
            const __half* gb = WgF + (size_t)g4*327680 +
                (size_t)((s*4+w)*20 + half*10)*512 + (size_t)lane*8;
            #pragma unroll
            for (int j=0;j<10;j++) gw[j] = *(const f16x8*)(gb + j*512);
            #pragma unroll
            for (int j=0;j<10;j++){
              const int kt = half*10 + j;
              #pragma unroll
              for (int c=0;c<4;c++){
                f16x8 a = (kt < 4)
                  ? *(const f16x8*)(&Xf[c][kt*512 + lane*8])
                  : *(const f16x8*)(&Af[c][(kt-4)*512 + lane*8]);
                gacc[c][g4] = __builtin_amdgcn_mfma_f32_16x16x32_f16(a, gw[j], gacc[c][g4], 0,0,0);
              }
            }
          }
        }
      }
    }

    // ===== phase 5: LSTM update + publish early; P2 + loss in shadow =====
    {
      POLLW();
      STAGE_ALL(Tf);
      __syncthreads();
      if (k < Kn-1){
        #pragma unroll
        for (int c=0;c<4;c++)
          #pragma unroll
          for (int r=0;r<4;r++){
            const int sr = rq*4 + r;
            const int er = pos[(k<<9) + (qg*4+c)*16 + sr];
            if (er >= 0){
              float ig = sigm(gacc[c][0][r] + vbi);
              float fg = sigm(gacc[c][1][r] + vbf);
              float og = sigm(gacc[c][2][r] + vbo);
              float ct = tanhf(gacc[c][3][r] + vbc);
              Creg[c][r] = fg*Creg[c][r] + ig*ct;
              Hreg[c][r] = og*tanhf(Creg[c][r]);
              ash(Hf + ((size_t)((qg*4+c)*16 + sr))*512 + jc, Hreg[c][r]);
            }
          }
      }
      PUBLISHW();                 // peers proceed to next event; P2/loss local below
      #pragma unroll 1
      for (int c=0;c<4;c++){
        f32x4 a4 = {0.f,0.f,0.f,0.f};
        #pragma unroll
        for (int j=0;j<4;j++){
          f16x8 a = *(const f16x8*)(&Af[c][(w*4+j)*512 + lane*8]);
          a4 = __builtin_amdgcn_mfma_f32_16x16x32_f16(a, wp2r[j], a4, 0,0,0);
        }
        float* o = outb + w*256 + (rq*4)*16 + cl;
        o[0]=a4[0]; o[16]=a4[1]; o[32]=a4[2]; o[48]=a4[3];
        __syncthreads();
        const int el = pos[(k<<9) + (qg*4+c)*16 + lrow];
        if (el >= 0){
          float p = outb[lrow*16+q4] + outb[256+lrow*16+q4]
                  + outb[512+lrow*16+q4] + outb[768+lrow*16+q4] + vbp2;
          const size_t xoff = ((size_t)(k*En+el))*Dn + s*16 + q4;
          float xo = X[xoff], mo = Mm[xoff];
          loss_loc += fabsf(xo - p)*mo;
          m_loc    += mo;
        }
        __syncthreads();
      }
    }
  }

  // block reduction -> global atomics
  #pragma unroll
  for (int off=32; off>0; off>>=1){
    loss_loc += __shfl_down(loss_loc, off);
    m_loc    += __shfl_down(m_loc, off);
  }
  if (lane == 0){ redbuf[w] = loss_loc; redbuf[4+w] = m_loc; }
  __syncthreads();
  if (t == 0){
    atomicAdd(acc+0, redbuf[0]+redbuf[1]+redbuf[2]+redbuf[3]);
    atomicAdd(acc+1, redbuf[4]+redbuf[5]+redbuf[6]+redbuf[7]);
  }
#undef POLLW
#undef PUBLISHW
#undef STAGE_ALL
}

__global__ void k_fin(const float* __restrict__ acc, float* __restrict__ out){
  if (threadIdx.x == 0){
    out[0] = acc[0];
    out[1] = acc[0]/acc[1];
  }
}

extern "C" void kernel_launch(void* const* d_in, const int* in_sizes, int n_in,
                              void* d_out, int out_size, void* d_ws, size_t ws_size,
                              hipStream_t stream)
{
  const float* X   = (const float*)d_in[0];
  const float* Mm  = (const float*)d_in[1];
  const int*  bidx = (const int*)d_in[2];
  const float* Wi  = (const float*)d_in[4];
  const float* bi  = (const float*)d_in[5];
  const float* Wf  = (const float*)d_in[6];
  const float* bff = (const float*)d_in[7];
  const float* Wo  = (const float*)d_in[8];
  const float* bo  = (const float*)d_in[9];
  const float* Wc  = (const float*)d_in[10];
  const float* bc  = (const float*)d_in[11];
  const float* W1  = (const float*)d_in[12];
  const float* b1  = (const float*)d_in[13];
  const float* W2  = (const float*)d_in[14];
  const float* b2  = (const float*)d_in[15];
  const float* Wp1 = (const float*)d_in[16];
  const float* bp1 = (const float*)d_in[17];
  const float* Wp2 = (const float*)d_in[18];
  const float* bp2 = (const float*)d_in[19];

  char* ws = (char*)d_ws;
  int*    pos = (int*)ws;
  float*  acc = (float*)(ws + 131072);
  int*    flg = (int*)(ws + 196608);
  __half* Hf  = (__half*)(ws + 1048576);
  __half* Tf  = (__half*)(ws + 1572864);
  __half* WF  = (__half*)(ws + 4194304);

  k_init   <<<512, 256, 0, stream>>>(pos, acc, flg, (uint32_t*)Hf);
  k_scatter<<<(Kn*En + 255)/256, 256, 0, stream>>>(bidx, pos);

  k_cvt_frag<<<(262144+255)/256, 256, 0, stream>>>(W1,  WF,          16, 512, 262144);
  k_cvt_frag<<<(262144+255)/256, 256, 0, stream>>>(W2,  WF + 262144, 16, 512, 262144);
  k_cvt_frag<<<(262144+255)/256, 256, 0, stream>>>(Wp1, WF + 524288, 16, 512, 262144);
  k_cvt_frag<<<(65536 +255)/256, 256, 0, stream>>>(Wp2, WF + 786432, 16, 128, 65536);
  k_cvt_frag<<<(327680+255)/256, 256, 0, stream>>>(Wi,  WF + 851968,            20, 512, 327680);
  k_cvt_frag<<<(327680+255)/256, 256, 0, stream>>>(Wf,  WF + 851968 + 327680,   20, 512, 327680);
  k_cvt_frag<<<(327680+255)/256, 256, 0, stream>>>(Wo,  WF + 851968 + 655360,   20, 512, 327680);
  k_cvt_frag<<<(327680+255)/256, 256, 0, stream>>>(Wc,  WF + 851968 + 983040,   20, 512, 327680);

  k_main<<<NBLK, NTH, 0, stream>>>(X, Mm, pos, WF, Hf, Tf,
                                   bi, bff, bo, bc, b1, b2, bp1, bp2, acc, flg);
  k_fin<<<1, 64, 0, stream>>>(acc, (float*)d_out);
}

// Round 11
// 5054.847 us; speedup vs baseline: 1.1071x; 1.1071x over previous
//
#include <hip/hip_runtime.h>
#include <hip/hip_fp16.h>
#include <stdint.h>

#define Kn 64
#define En 256
#define Bn 512
#define Hn 512
#define Dn 128
#define NBLK 256
#define NTH  256
#define DT_C 0.05f

// ---------- shared ws layout ----------
// 0        pos   int[Kn*Bn] (128KB)
// 131072   acc   float[2]
// 131200   ctr   int[1024]            (R7 fallback barrier counters)
// 196608   flg   int[8192] (32KB)     (new-path flags, 128B stride)
// 1048576  Hf16  __half[512][512]     (R7 fallback)
// 1572864  Tf16  __half[512][512]     (R7 fallback)
// 4194304  WF    frag-swizzled f16 weights (4.33MB, both paths)
// ---- new path only ----
// 8650752  Qb    __half [32g][2][8][8192]   (8MB)
// 17039360 Rb    float  [32g][8][2048]      (2MB)
// 19136512 Hp    __half [32g][8][1024]      (512KB)  -> end 19660800
#define WS_NEED_PS 19660800ULL

typedef _Float16 f16x8 __attribute__((ext_vector_type(8)));
typedef float    f32x4 __attribute__((ext_vector_type(4)));
typedef unsigned long long u64;

__device__ __forceinline__ float sigm(float x){ return 1.0f/(1.0f + __expf(-x)); }

__device__ __forceinline__ u64 ald(const u64* p){
  return __hip_atomic_load(p, __ATOMIC_RELAXED, __HIP_MEMORY_SCOPE_AGENT);
}
__device__ __forceinline__ void ast(u64* p, u64 v){
  __hip_atomic_store(p, v, __ATOMIC_RELAXED, __HIP_MEMORY_SCOPE_AGENT);
}
__device__ __forceinline__ uint32_t ald32(const uint32_t* p){
  return __hip_atomic_load(p, __ATOMIC_RELAXED, __HIP_MEMORY_SCOPE_AGENT);
}
__device__ __forceinline__ void ast32(uint32_t* p, uint32_t v){
  __hip_atomic_store(p, v, __ATOMIC_RELAXED, __HIP_MEMORY_SCOPE_AGENT);
}

union HU { __half h[8]; u64 q[2]; };

__global__ void k_init(int* __restrict__ pos, float* __restrict__ acc,
                       int* __restrict__ ctr, int* __restrict__ flg,
                       uint32_t* __restrict__ hf){
  int i = blockIdx.x*blockDim.x + threadIdx.x;
  if (i < Kn*Bn) pos[i] = -1;
  if (i < 2) acc[i] = 0.0f;
  if (i < 1024) ctr[i] = 0;
  if (i < 8192) flg[i] = 0;
  if (i < Hn*Hn/2) hf[i] = 0;
}

__global__ void k_scatter(const int* __restrict__ bidx, int* __restrict__ pos){
  int i = blockIdx.x*blockDim.x + threadIdx.x;
  if (i < Kn*En){
    int k = i >> 8;
    int e = i & (En-1);
    pos[(k << 9) | bidx[i]] = e;
  }
}

// frag-swizzle: element = W[T*32+(l>>4)*8+e][C*16+(l&15)], idx=((C*KT+T)*64+l)*8+e
__global__ void k_cvt_frag(const float* __restrict__ src, __half* __restrict__ dst,
                           int KT, int N, int n){
  int i = blockIdx.x*blockDim.x + threadIdx.x;
  if (i >= n) return;
  int C = i / (KT*512);
  int r = i % (KT*512);
  int T = r >> 9;
  int q = r & 511;
  int l = q >> 3, e = q & 7;
  int srow = T*32 + ((l>>4)<<3) + e;
  int scol = C*16 + (l&15);
  dst[i] = __float2half(src[(size_t)srow*N + scol]);
}

__device__ __forceinline__ f32x4 mv16(const __half* Af, const f16x8* Wr, int lane){
  f32x4 a = {0.f,0.f,0.f,0.f};
  #pragma unroll
  for (int kt=0; kt<16; kt++){
    f16x8 av = *(const f16x8*)(Af + kt*512 + lane*8);
    a = __builtin_amdgcn_mfma_f32_16x16x32_f16(av, Wr[kt], a, 0,0,0);
  }
  return a;
}

// ======================= NEW: 3-exchange/event kernel =======================
__global__ __launch_bounds__(NTH, 1) void k_main_ps(
  const float* __restrict__ X, const float* __restrict__ Mm,
  const int* __restrict__ pos, const __half* __restrict__ WF,
  __half* __restrict__ Qb, float* __restrict__ Rb, __half* __restrict__ Hp,
  const float* __restrict__ bi_, const float* __restrict__ bf_,
  const float* __restrict__ bo_, const float* __restrict__ bc_,
  const float* __restrict__ b1_, const float* __restrict__ b2_,
  const float* __restrict__ bp1_, const float* __restrict__ bp2_,
  float* __restrict__ acc, int* __restrict__ flg)
{
  const __half* W1F  = WF;
  const __half* W2F  = WF + 262144;
  const __half* Wp1F = WF + 524288;
  const __half* Wp2F = WF + 786432;
  const __half* WgF  = WF + 851968;

  const int t    = threadIdx.x;
  const int bid  = blockIdx.x;
  const int s    = bid & 7;      // slice (same-s blocks share XCD L2 for weights; perf-only)
  const int g    = bid >> 3;     // group 0..31
  const int w    = t >> 6;
  const int lane = t & 63;
  int* flgbase = flg + g*8*32;

  __shared__ __align__(16) __half Afrag[8192];   // 16KB  h A-frags [16kt][64][8]
  __shared__ __align__(16) __half Xfrag[2048];   // 4KB
  __shared__ __align__(16) __half T1sm[1024];    // 2KB   [16 rows][64 cols]
  __shared__ __align__(16) float  hm[8192];      // 32KB  full h master f32 [16][512]
  __shared__ __align__(16) float  outg[4096];    // 16KB  gate route [4][16][64]
  __shared__ __align__(16) __half outq[8192];    // 16KB  Q route [16][512]
  __shared__ float b2s[512];
  __shared__ int   posk[16];
  __shared__ float redbuf[8];

  // per-thread scalars
  const float vb1r  = b1_ [s*64 + w*16 + (lane&15)];
  const float vbp1r = bp1_[s*64 + w*16 + (lane&15)];
  const float vbp2  = bp2_[s*16 + (t&15)];
  float vbi[4], vbf[4], vbo[4], vbc[4];
  #pragma unroll
  for (int j=0;j<4;j++){
    const int c = s*64 + (t&15)*4 + j;
    vbi[j]=bi_[c]; vbf[j]=bf_[c]; vbo[j]=bo_[c]; vbc[j]=bc_[c];
  }
  float Creg[4] = {0,0,0,0};

  // weight hoists (per wave)
  f16x8 W1r[16], W2r[16], Wp1r[16], Wp2r[4];
  {
    #pragma unroll
    for (int kt=0; kt<16; kt++){
      W1r[kt]  = *(const f16x8*)(W1F  + (size_t)((s*4+w)*16 + kt)*512 + lane*8);
      Wp1r[kt] = *(const f16x8*)(Wp1F + (size_t)((s*4+w)*16 + kt)*512 + lane*8);
    }
    #pragma unroll
    for (int c2=0;c2<8;c2++)
      #pragma unroll
      for (int j=0;j<2;j++)
        W2r[c2*2+j] = *(const f16x8*)(W2F + (size_t)((w*8+c2)*16 + 2*s + j)*512 + lane*8);
    #pragma unroll
    for (int c2=0;c2<2;c2++)
      #pragma unroll
      for (int j=0;j<2;j++)
        Wp2r[c2*2+j] = *(const f16x8*)(Wp2F + (size_t)((w*2+c2)*16 + 2*s + j)*512 + lane*8);
  }

  for (int i=t;i<8192;i+=NTH){ hm[i]=0.f; Afrag[i]=__float2half(0.f); }
  for (int i=t;i<512;i+=NTH) b2s[i]=b2_[i];
  __syncthreads();

  float loss_loc=0.f, m_loc=0.f;
  int rnd = 0;

#define QSLOT(G,ST,R) (((size_t)(G)*2 + (ST))*8 + (R))*8192

#define GSYNC() do{                                                          \
    asm volatile("s_waitcnt vmcnt(0)" ::: "memory");                         \
    __syncthreads();                                                         \
    rnd++;                                                                   \
    if (t == 0)                                                              \
      __hip_atomic_store(flgbase + s*32, rnd, __ATOMIC_RELAXED,              \
                         __HIP_MEMORY_SCOPE_AGENT);                          \
    if (t < 8){                                                              \
      while (__hip_atomic_load(flgbase + t*32, __ATOMIC_RELAXED,             \
                               __HIP_MEMORY_SCOPE_AGENT) < rnd)              \
        __builtin_amdgcn_s_sleep(1);                                         \
    }                                                                        \
    __syncthreads();                                                         \
  }while(0)

#define EULER_STEP(ST) do{                                                   \
    f32x4 a1 = mv16(Afrag, W1r, lane);                                       \
    _Pragma("unroll")                                                        \
    for (int i=0;i<4;i++)                                                    \
      T1sm[((lane>>4)*4+i)*64 + w*16 + (lane&15)] =                          \
        __float2half(tanhf(a1[i]+vb1r));                                     \
    __syncthreads();                                                         \
    f32x4 qa[8];                                                             \
    _Pragma("unroll") for (int c2=0;c2<8;c2++) qa[c2]=(f32x4){0,0,0,0};      \
    _Pragma("unroll")                                                        \
    for (int j=0;j<2;j++){                                                   \
      f16x8 av = *(const f16x8*)(T1sm + (lane&15)*64 + j*32 + (lane>>4)*8);  \
      _Pragma("unroll")                                                      \
      for (int c2=0;c2<8;c2++)                                               \
        qa[c2] = __builtin_amdgcn_mfma_f32_16x16x32_f16(av, W2r[c2*2+j],     \
                                                        qa[c2], 0,0,0);      \
    }                                                                        \
    _Pragma("unroll")                                                        \
    for (int c2=0;c2<8;c2++){                                                \
      const int col = (w*8+c2)*16 + (lane&15);                               \
      _Pragma("unroll")                                                      \
      for (int i=0;i<4;i++)                                                  \
        outq[((lane>>4)*4+i)*512 + col] = __float2half(qa[c2][i]);           \
    }                                                                        \
    __syncthreads();                                                         \
    { const int qL=t&15, kt=t>>4;                                            \
      u64* dst = (u64*)(Qb + QSLOT(g,(ST),s) + kt*512 + qL*32);              \
      _Pragma("unroll")                                                      \
      for (int li=0;li<4;li++){                                              \
        const int L=qL*4+li;                                                 \
        const u64* sp = (const u64*)(outq + (L&15)*512 + kt*32 + (L>>4)*8);  \
        ast(dst+li*2,   sp[0]);                                              \
        ast(dst+li*2+1, sp[1]);                                              \
      } }                                                                    \
    GSYNC();                                                                 \
  }while(0)

#define REDUCE(ST) do{                                                       \
    const int qL=t&15, kt=t>>4;                                              \
    float sum[32];                                                           \
    _Pragma("unroll") for (int i=0;i<32;i++) sum[i]=0.f;                     \
    _Pragma("unroll")                                                        \
    for (int r=0;r<8;r++){                                                   \
      const u64* qp = (const u64*)(Qb + QSLOT(g,(ST),r) + kt*512 + qL*32);   \
      u64 vv[8];                                                             \
      _Pragma("unroll") for (int i=0;i<8;i++) vv[i]=ald(qp+i);               \
      _Pragma("unroll")                                                      \
      for (int li=0;li<4;li++){                                              \
        _Pragma("unroll")                                                    \
        for (int h2=0;h2<2;h2++){                                            \
          u64 xx = vv[li*2+h2];                                              \
          _Pragma("unroll")                                                  \
          for (int e=0;e<4;e++)                                              \
            sum[li*8+h2*4+e] +=                                              \
              __half2float(__ushort_as_half((unsigned short)(xx>>(16*e))));  \
        } } }                                                                \
    _Pragma("unroll")                                                        \
    for (int li=0;li<4;li++){                                                \
      const int L=qL*4+li, row=L&15, kb=kt*32+(L>>4)*8;                      \
      _Pragma("unroll")                                                      \
      for (int e=0;e<8;e++){                                                 \
        float nh = hm[row*512+kb+e] + DT_C*(sum[li*8+e] + b2s[kb+e]);        \
        hm[row*512+kb+e]=nh;                                                 \
        Afrag[kt*512+L*8+e]=__float2half(nh);                                \
      } }                                                                    \
    __syncthreads();                                                         \
  }while(0)

  for (int k=0; k<Kn; k++){
    // ---------- PH_A: fold (loss k-1, merge h') then Euler step 1 ----------
    if (k > 0){
      {
        const int lrow=t>>4, q4=t&15;
        const int ep = posk[lrow];
        if (ep >= 0){
          float p = vbp2;
          #pragma unroll
          for (int r=0;r<8;r++)
            p += __uint_as_float(ald32((const uint32_t*)Rb +
                   (size_t)(g*8+r)*2048 + s*256 + lrow*16 + q4));
          const size_t xo = ((size_t)((k-1)*En+ep))*Dn + s*16 + q4;
          float mo = Mm[xo];
          loss_loc += fabsf(X[xo]-p)*mo; m_loc += mo;
        }
      }
      {
        const int qL=t&15, kt=t>>4, r=kt>>1, kt2=kt&1;
        const u64* hp = (const u64*)(Hp + (size_t)(g*8+r)*1024 + kt2*512 + qL*32);
        #pragma unroll
        for (int li=0;li<4;li++){
          const int L=qL*4+li, row=L&15;
          if (posk[row] >= 0){
            u64 lo = ald(hp + li*2), hi2 = ald(hp + li*2 + 1);
            #pragma unroll
            for (int e=0;e<4;e++){
              __half hv = __ushort_as_half((unsigned short)(lo >> (16*e)));
              hm[row*512 + kt*32 + (L>>4)*8 + e] = __half2float(hv);
              Afrag[kt*512 + L*8 + e] = hv;
            }
            #pragma unroll
            for (int e=0;e<4;e++){
              __half hv = __ushort_as_half((unsigned short)(hi2 >> (16*e)));
              hm[row*512 + kt*32 + (L>>4)*8 + 4 + e] = __half2float(hv);
              Afrag[kt*512 + L*8 + 4 + e] = hv;
            }
          }
        }
      }
      __syncthreads();
    }
    EULER_STEP(0);

    // ---------- PH_B: reduce Q1 then Euler step 2 ----------
    REDUCE(0);
    EULER_STEP(1);

    // ---------- PH_C: reduce Q2; p1/p2 partial; gates; LSTM; publish ----------
    REDUCE(1);
    if (t < 16) posk[t] = pos[(k<<9) + g*16 + t];
    if (t < 64){
      const int ar = t & 15, ch = t >> 4;
      const int e = pos[(k<<9) + g*16 + ar];
      float xv[32];
      if (e >= 0){
        const float4* xp = (const float4*)(X + ((size_t)(k*En+e))*Dn + ch*32);
        #pragma unroll
        for (int i=0;i<8;i++){
          float4 f = xp[i];
          xv[4*i]=f.x; xv[4*i+1]=f.y; xv[4*i+2]=f.z; xv[4*i+3]=f.w;
        }
      } else {
        #pragma unroll
        for (int i=0;i<32;i++) xv[i]=0.f;
      }
      #pragma unroll
      for (int kg=0;kg<4;kg++){
        HU u;
        #pragma unroll
        for (int e8=0;e8<8;e8++) u.h[e8] = __float2half(xv[kg*8+e8]);
        u64* d = (u64*)(Xfrag + ch*512 + (ar + 16*kg)*8);
        d[0] = u.q[0]; d[1] = u.q[1];
      }
    }
    {
      f32x4 p1 = mv16(Afrag, Wp1r, lane);
      #pragma unroll
      for (int i=0;i<4;i++)
        T1sm[((lane>>4)*4+i)*64 + w*16 + (lane&15)] =
          __float2half(fmaxf(p1[i]+vbp1r, 0.f));
    }
    __syncthreads();
    // p2 partial -> direct R publish
    #pragma unroll
    for (int c2=0;c2<2;c2++){
      f32x4 a4 = {0,0,0,0};
      #pragma unroll
      for (int j=0;j<2;j++){
        f16x8 av = *(const f16x8*)(T1sm + (lane&15)*64 + j*32 + (lane>>4)*8);
        a4 = __builtin_amdgcn_mfma_f32_16x16x32_f16(av, Wp2r[c2*2+j], a4, 0,0,0);
      }
      const int ct = w*2 + c2;
      uint32_t* rb = (uint32_t*)Rb + (size_t)(g*8+s)*2048 + ct*256 + (lane&15);
      #pragma unroll
      for (int i=0;i<4;i++)
        ast32(rb + ((lane>>4)*4+i)*16, __float_as_uint(a4[i]));
    }
    if (k < Kn-1){
      #pragma unroll 1
      for (int i4=0;i4<4;i4++){
        const int Cg = w*32 + s*4 + i4;
        const __half* wb = WgF + (size_t)Cg*20*512;
        f32x4 a4 = {0,0,0,0};
        #pragma unroll 4
        for (int kt=0;kt<4;kt++){
          f16x8 av = *(const f16x8*)(Xfrag + kt*512 + lane*8);
          f16x8 bv = *(const f16x8*)(wb + kt*512 + lane*8);
          a4 = __builtin_amdgcn_mfma_f32_16x16x32_f16(av, bv, a4, 0,0,0);
        }
        #pragma unroll 4
        for (int kt=4;kt<20;kt++){
          f16x8 av = *(const f16x8*)(Afrag + (kt-4)*512 + lane*8);
          f16x8 bv = *(const f16x8*)(wb + kt*512 + lane*8);
          a4 = __builtin_amdgcn_mfma_f32_16x16x32_f16(av, bv, a4, 0,0,0);
        }
        #pragma unroll
        for (int i=0;i<4;i++)
          outg[w*1024 + ((lane>>4)*4+i)*64 + i4*16 + (lane&15)] = a4[i];
      }
      __syncthreads();
      {
        const int lrow=t>>4, q4=t&15;
        const int eo = posk[lrow];
        unsigned short hb[4];
        if (eo >= 0){
          #pragma unroll
          for (int j=0;j<4;j++){
            const int col = q4*4+j;
            float pi = outg[0*1024 + lrow*64 + col];
            float pf = outg[1*1024 + lrow*64 + col];
            float po = outg[2*1024 + lrow*64 + col];
            float pc = outg[3*1024 + lrow*64 + col];
            float ig=sigm(pi+vbi[j]), fg=sigm(pf+vbf[j]);
            float og=sigm(po+vbo[j]), ctv=tanhf(pc+vbc[j]);
            Creg[j] = fg*Creg[j] + ig*ctv;
            hb[j] = __half_as_ushort(__float2half(og*tanhf(Creg[j])));
          }
        } else {
          #pragma unroll
          for (int j=0;j<4;j++)
            hb[j] = __half_as_ushort(__float2half(hm[lrow*512 + s*64 + q4*4 + j]));
        }
        u64 pk = (u64)hb[0] | ((u64)hb[1]<<16) | ((u64)hb[2]<<32) | ((u64)hb[3]<<48);
        const int kt2=q4>>3, ln=lrow+16*((q4&7)>>1), e0=(q4*4)&7;
        ast((u64*)(Hp + (size_t)(g*8+s)*1024 + kt2*512 + ln*8 + e0), pk);
      }
    }
    GSYNC();
  }

  // epilogue: loss for event Kn-1 (R published in last PH_C; posk holds its events)
  {
    const int lrow=t>>4, q4=t&15;
    const int ep = posk[lrow];
    if (ep >= 0){
      float p = vbp2;
      #pragma unroll
      for (int r=0;r<8;r++)
        p += __uint_as_float(ald32((const uint32_t*)Rb +
               (size_t)(g*8+r)*2048 + s*256 + lrow*16 + q4));
      const size_t xo = ((size_t)((Kn-1)*En+ep))*Dn + s*16 + q4;
      float mo = Mm[xo];
      loss_loc += fabsf(X[xo]-p)*mo; m_loc += mo;
    }
  }

  #pragma unroll
  for (int off=32; off>0; off>>=1){
    loss_loc += __shfl_down(loss_loc, off);
    m_loc    += __shfl_down(m_loc, off);
  }
  if (lane == 0){ redbuf[w] = loss_loc; redbuf[4+w] = m_loc; }
  __syncthreads();
  if (t == 0){
    atomicAdd(acc+0, redbuf[0]+redbuf[1]+redbuf[2]+redbuf[3]);
    atomicAdd(acc+1, redbuf[4]+redbuf[5]+redbuf[6]+redbuf[7]);
  }
#undef QSLOT
#undef GSYNC
#undef EULER_STEP
#undef REDUCE
}

// ======================= R7 fallback (proven 1916us) =======================
__device__ __forceinline__ void gsync7(int* c, int tgt){
  asm volatile("s_waitcnt vmcnt(0)" ::: "memory");
  __syncthreads();
  if (threadIdx.x == 0){
    __hip_atomic_fetch_add(c, 1, __ATOMIC_RELAXED, __HIP_MEMORY_SCOPE_AGENT);
    while (__hip_atomic_load(c, __ATOMIC_RELAXED, __HIP_MEMORY_SCOPE_AGENT) < tgt)
      __builtin_amdgcn_s_sleep(1);
  }
  __syncthreads();
}

__global__ __launch_bounds__(NTH, 1) void k_main_r7(
  const float* __restrict__ X, const float* __restrict__ Mm,
  const int* __restrict__ pos, const __half* __restrict__ WF,
  __half* __restrict__ Hf, __half* __restrict__ Tf,
  const float* __restrict__ bi_, const float* __restrict__ bf_,
  const float* __restrict__ bo_, const float* __restrict__ bc_,
  const float* __restrict__ b1_, const float* __restrict__ b2_,
  const float* __restrict__ bp1_, const float* __restrict__ bp2_,
  float* __restrict__ acc, int* __restrict__ ctrbase)
{
  const __half* W1F  = WF;
  const __half* W2F  = WF + 262144;
  const __half* Wp1F = WF + 524288;
  const __half* Wp2F = WF + 786432;
  const __half* WgF  = WF + 851968;

  const int t    = threadIdx.x;
  const int bid  = blockIdx.x;
  const int s    = bid & 7;
  const int g    = bid >> 3;
  const int w    = t >> 6;
  const int lane = t & 63;
  int* ctr = ctrbase + g*32;

  __shared__ __align__(16) __half Afrag[16*512];
  __shared__ __align__(16) __half Xfrag[4*512];
  __shared__ __align__(16) float  outb[20*256];
  __shared__ float redbuf[8];

  const int row = t >> 4;
  const int q4  = t & 15;
  const int sc  = s*64 + q4*4;
  float Hreg[4] = {0,0,0,0};
  float Creg[4] = {0,0,0,0};
  float vb1[4], vb2[4], vbp1[4], vbi[4], vbf[4], vbo[4], vbc[4];
  #pragma unroll
  for (int i=0;i<4;i++){
    vb1[i]=b1_[sc+i]; vb2[i]=b2_[sc+i]; vbp1[i]=bp1_[sc+i];
    vbi[i]=bi_[sc+i]; vbf[i]=bf_[sc+i]; vbo[i]=bo_[sc+i]; vbc[i]=bc_[sc+i];
  }
  const float vbp2 = bp2_[s*16 + q4];

  f16x8 W1r[16], W2r[16], Wp1r[16];
  {
    const size_t cb = (size_t)(s*4 + w)*16*512 + (size_t)lane*8;
    #pragma unroll
    for (int kt=0; kt<16; kt++){
      W1r[kt]  = *(const f16x8*)(W1F  + cb + kt*512);
      W2r[kt]  = *(const f16x8*)(W2F  + cb + kt*512);
      Wp1r[kt] = *(const f16x8*)(Wp1F + cb + kt*512);
    }
  }

  float loss_loc = 0.f, m_loc = 0.f;
  int round = 0;
  const int grow = g*16 + row;

  for (int k=0;k<Kn;k++){
    const int epos = pos[(k<<9) + grow];
    #pragma unroll 1
    for (int ph=0; ph<4; ph++){
      const __half* srcb = (ph & 1) ? Tf : Hf;
      {
        const int ar = t & 15, ch = t >> 4;
        const u64* sp = (const u64*)(srcb + ((size_t)(g*16+ar))*512 + ch*32);
        u64 v[8];
        #pragma unroll
        for (int i=0;i<8;i++) v[i] = ald(sp+i);
        #pragma unroll
        for (int kg=0;kg<4;kg++){
          u64* d = (u64*)(Afrag + ch*512 + (ar + 16*kg)*8);
          d[0] = v[2*kg]; d[1] = v[2*kg+1];
        }
      }
      __syncthreads();
      {
        f32x4 a4 = {0,0,0,0};
        if (!(ph & 1)) a4 = mv16(Afrag, W1r, lane);
        else           a4 = mv16(Afrag, W2r, lane);
        float* o = outb + w*256 + ((lane>>4)*4)*16 + (lane&15);
        o[0]=a4[0]; o[16]=a4[1]; o[32]=a4[2]; o[48]=a4[3];
      }
      __syncthreads();
      {
        const float* o = outb + (q4>>2)*256 + row*16 + (q4&3)*4;
        float v0=o[0], v1=o[1], v2=o[2], v3=o[3];
        HU u;
        if (!(ph & 1)){
          u.h[0]=__float2half(tanhf(v0+vb1[0])); u.h[1]=__float2half(tanhf(v1+vb1[1]));
          u.h[2]=__float2half(tanhf(v2+vb1[2])); u.h[3]=__float2half(tanhf(v3+vb1[3]));
          ast((u64*)(Tf + (size_t)grow*512 + sc), u.q[0]);
        } else {
          Hreg[0] += DT_C*(v0+vb2[0]); Hreg[1] += DT_C*(v1+vb2[1]);
          Hreg[2] += DT_C*(v2+vb2[2]); Hreg[3] += DT_C*(v3+vb2[3]);
          u.h[0]=__float2half(Hreg[0]); u.h[1]=__float2half(Hreg[1]);
          u.h[2]=__float2half(Hreg[2]); u.h[3]=__float2half(Hreg[3]);
          ast((u64*)(Hf + (size_t)grow*512 + sc), u.q[0]);
        }
      }
      gsync7(ctr, 8*(++round));
    }
    {
      {
        const int ar = t & 15, ch = t >> 4;
        const u64* sp = (const u64*)(Hf + ((size_t)(g*16+ar))*512 + ch*32);
        u64 v[8];
        #pragma unroll
        for (int i=0;i<8;i++) v[i] = ald(sp+i);
        #pragma unroll
        for (int kg=0;kg<4;kg++){
          u64* d = (u64*)(Afrag + ch*512 + (ar + 16*kg)*8);
          d[0] = v[2*kg]; d[1] = v[2*kg+1];
        }
      }
      if (t < 64){
        const int ar = t & 15, ch = t >> 4;
        const int e = pos[(k<<9) + g*16 + ar];
        float xv[32];
        if (e >= 0){
          const float4* xp = (const float4*)(X + ((size_t)(k*En+e))*Dn + ch*32);
          #pragma unroll
          for (int i=0;i<8;i++){
            float4 f = xp[i];
            xv[4*i]=f.x; xv[4*i+1]=f.y; xv[4*i+2]=f.z; xv[4*i+3]=f.w;
          }
        } else {
          #pragma unroll
          for (int i=0;i<32;i++) xv[i]=0.f;
        }
        #pragma unroll
        for (int kg=0;kg<4;kg++){
          HU u;
          #pragma unroll
          for (int e8=0;e8<8;e8++) u.h[e8] = __float2half(xv[kg*8+e8]);
          u64* d = (u64*)(Xfrag + ch*512 + (ar + 16*kg)*8);
          d[0] = u.q[0]; d[1] = u.q[1];
        }
      }
      __syncthreads();
      {
        f32x4 a4 = mv16(Afrag, Wp1r, lane);
        float* o = outb + (16+w)*256 + ((lane>>4)*4)*16 + (lane&15);
        o[0]=a4[0]; o[16]=a4[1]; o[32]=a4[2]; o[48]=a4[3];
      }
      #pragma unroll 1
      for (int i=0;i<4;i++){
        const int Cg = w*32 + s*4 + i;
        const __half* wb = WgF + (size_t)Cg*20*512;
        f32x4 a4 = {0,0,0,0};
        #pragma unroll 4
        for (int kt=0; kt<4; kt++){
          f16x8 a = *(const f16x8*)(Xfrag + kt*512 + lane*8);
          f16x8 b = *(const f16x8*)(wb + kt*512 + lane*8);
          a4 = __builtin_amdgcn_mfma_f32_16x16x32_f16(a, b, a4, 0,0,0);
        }
        #pragma unroll 4
        for (int kt=4; kt<20; kt++){
          f16x8 a = *(const f16x8*)(Afrag + (kt-4)*512 + lane*8);
          f16x8 b = *(const f16x8*)(wb + kt*512 + lane*8);
          a4 = __builtin_amdgcn_mfma_f32_16x16x32_f16(a, b, a4, 0,0,0);
        }
        float* o = outb + (w*4+i)*256 + ((lane>>4)*4)*16 + (lane&15);
        o[0]=a4[0]; o[16]=a4[1]; o[32]=a4[2]; o[48]=a4[3];
      }
      __syncthreads();
      {
        const float* o = outb + (16+(q4>>2))*256 + row*16 + (q4&3)*4;
        HU u;
        u.h[0]=__float2half(fmaxf(o[0]+vbp1[0],0.f));
        u.h[1]=__float2half(fmaxf(o[1]+vbp1[1],0.f));
        u.h[2]=__float2half(fmaxf(o[2]+vbp1[2],0.f));
        u.h[3]=__float2half(fmaxf(o[3]+vbp1[3],0.f));
        ast((u64*)(Tf + (size_t)grow*512 + sc), u.q[0]);
      }
      gsync7(ctr, 8*(++round));
    }
    {
      {
        const int ar = t & 15, ch = t >> 4;
        const u64* sp = (const u64*)(Tf + ((size_t)(g*16+ar))*512 + ch*32);
        u64 v[8];
        #pragma unroll
        for (int i=0;i<8;i++) v[i] = ald(sp+i);
        #pragma unroll
        for (int kg=0;kg<4;kg++){
          u64* d = (u64*)(Afrag + ch*512 + (ar + 16*kg)*8);
          d[0] = v[2*kg]; d[1] = v[2*kg+1];
        }
      }
      __syncthreads();
      {
        const __half* wb = Wp2F + (size_t)s*16*512;
        f32x4 a4 = {0,0,0,0};
        #pragma unroll
        for (int kt2=0; kt2<4; kt2++){
          const int kt = w*4 + kt2;
          f16x8 a = *(const f16x8*)(Afrag + kt*512 + lane*8);
          f16x8 b = *(const f16x8*)(wb + kt*512 + lane*8);
          a4 = __builtin_amdgcn_mfma_f32_16x16x32_f16(a, b, a4, 0,0,0);
        }
        float* o = outb + (16+w)*256 + ((lane>>4)*4)*16 + (lane&15);
        o[0]=a4[0]; o[16]=a4[1]; o[32]=a4[2]; o[48]=a4[3];
      }
      if (epos >= 0){
        const int sub = q4 >> 2, off = row*16 + (q4&3)*4;
        const float4 pi = *(const float4*)(outb + (0*4+sub)*256 + off);
        const float4 pf = *(const float4*)(outb + (1*4+sub)*256 + off);
        const float4 po = *(const float4*)(outb + (2*4+sub)*256 + off);
        const float4 pc = *(const float4*)(outb + (3*4+sub)*256 + off);
        HU hu;
        const float gi[4]={pi.x,pi.y,pi.z,pi.w}, gf[4]={pf.x,pf.y,pf.z,pf.w};
        const float go[4]={po.x,po.y,po.z,po.w}, gc[4]={pc.x,pc.y,pc.z,pc.w};
        #pragma unroll
        for (int i=0;i<4;i++){
          float ig = sigm(gi[i] + vbi[i]);
          float fg = sigm(gf[i] + vbf[i]);
          float og = sigm(go[i] + vbo[i]);
          float ct = tanhf(gc[i] + vbc[i]);
          Creg[i] = fg*Creg[i] + ig*ct;
          Hreg[i] = og*tanhf(Creg[i]);
          hu.h[i] = __float2half(Hreg[i]);
        }
        ast((u64*)(Hf + (size_t)grow*512 + sc), hu.q[0]);
      }
      __syncthreads();
      if (epos >= 0){
        float p = outb[16*256 + row*16+q4] + outb[17*256 + row*16+q4]
                + outb[18*256 + row*16+q4] + outb[19*256 + row*16+q4] + vbp2;
        const int d = s*16 + q4;
        float xo = X[((size_t)(k*En+epos))*Dn + d];
        float mo = Mm[((size_t)(k*En+epos))*Dn + d];
        loss_loc += fabsf(xo - p)*mo;
        m_loc    += mo;
      }
      gsync7(ctr, 8*(++round));
    }
  }

  #pragma unroll
  for (int off=32; off>0; off>>=1){
    loss_loc += __shfl_down(loss_loc, off);
    m_loc    += __shfl_down(m_loc, off);
  }
  if (lane == 0){ redbuf[w] = loss_loc; redbuf[4+w] = m_loc; }
  __syncthreads();
  if (t == 0){
    atomicAdd(acc+0, redbuf[0]+redbuf[1]+redbuf[2]+redbuf[3]);
    atomicAdd(acc+1, redbuf[4]+redbuf[5]+redbuf[6]+redbuf[7]);
  }
}

__global__ void k_fin(const float* __restrict__ acc, float* __restrict__ out){
  if (threadIdx.x == 0){
    out[0] = acc[0];
    out[1] = acc[0]/acc[1];
  }
}

extern "C" void kernel_launch(void* const* d_in, const int* in_sizes, int n_in,
                              void* d_out, int out_size, void* d_ws, size_t ws_size,
                              hipStream_t stream)
{
  const float* X   = (const float*)d_in[0];
  const float* Mm  = (const float*)d_in[1];
  const int*  bidx = (const int*)d_in[2];
  const float* Wi  = (const float*)d_in[4];
  const float* bi  = (const float*)d_in[5];
  const float* Wf  = (const float*)d_in[6];
  const float* bff = (const float*)d_in[7];
  const float* Wo  = (const float*)d_in[8];
  const float* bo  = (const float*)d_in[9];
  const float* Wc  = (const float*)d_in[10];
  const float* bc  = (const float*)d_in[11];
  const float* W1  = (const float*)d_in[12];
  const float* b1  = (const float*)d_in[13];
  const float* W2  = (const float*)d_in[14];
  const float* b2  = (const float*)d_in[15];
  const float* Wp1 = (const float*)d_in[16];
  const float* bp1 = (const float*)d_in[17];
  const float* Wp2 = (const float*)d_in[18];
  const float* bp2 = (const float*)d_in[19];

  char* ws = (char*)d_ws;
  int*    pos = (int*)ws;
  float*  acc = (float*)(ws + 131072);
  int*    ctr = (int*)(ws + 131200);
  int*    flg = (int*)(ws + 196608);
  __half* Hf  = (__half*)(ws + 1048576);
  __half* Tf  = (__half*)(ws + 1572864);
  __half* WF  = (__half*)(ws + 4194304);
  __half* Qb  = (__half*)(ws + 8650752);
  float*  Rb  = (float*)(ws + 17039360);
  __half* Hp  = (__half*)(ws + 19136512);

  k_init   <<<512, 256, 0, stream>>>(pos, acc, ctr, flg, (uint32_t*)Hf);
  k_scatter<<<(Kn*En + 255)/256, 256, 0, stream>>>(bidx, pos);

  k_cvt_frag<<<(262144+255)/256, 256, 0, stream>>>(W1,  WF,          16, 512, 262144);
  k_cvt_frag<<<(262144+255)/256, 256, 0, stream>>>(W2,  WF + 262144, 16, 512, 262144);
  k_cvt_frag<<<(262144+255)/256, 256, 0, stream>>>(Wp1, WF + 524288, 16, 512, 262144);
  k_cvt_frag<<<(65536 +255)/256, 256, 0, stream>>>(Wp2, WF + 786432, 16, 128, 65536);
  k_cvt_frag<<<(327680+255)/256, 256, 0, stream>>>(Wi,  WF + 851968,            20, 512, 327680);
  k_cvt_frag<<<(327680+255)/256, 256, 0, stream>>>(Wf,  WF + 851968 + 327680,   20, 512, 327680);
  k_cvt_frag<<<(327680+255)/256, 256, 0, stream>>>(Wo,  WF + 851968 + 655360,   20, 512, 327680);
  k_cvt_frag<<<(327680+255)/256, 256, 0, stream>>>(Wc,  WF + 851968 + 983040,   20, 512, 327680);

  if (ws_size >= WS_NEED_PS){
    k_main_ps<<<NBLK, NTH, 0, stream>>>(X, Mm, pos, WF, Qb, Rb, Hp,
                                        bi, bff, bo, bc, b1, b2, bp1, bp2, acc, flg);
  } else {
    k_main_r7<<<NBLK, NTH, 0, stream>>>(X, Mm, pos, WF, Hf, Tf,
                                        bi, bff, bo, bc, b1, b2, bp1, bp2, acc, ctr);
  }
  k_fin<<<1, 64, 0, stream>>>(acc, (float*)d_out);
}

// Round 12
// 1892.699 us; speedup vs baseline: 2.9566x; 2.6707x over previous
//
#include <hip/hip_runtime.h>
#include <hip/hip_fp16.h>
#include <stdint.h>

#define Kn 64
#define En 256
#define Bn 512
#define Hn 512
#define Dn 128
#define NBLK 256
#define NTH  256
#define DT_C 0.05f

// ws layout (bytes):
//   0        pos   int[Kn*Bn]           (128 KB)
//   131072   acc   float[2]
//   196608   flg   int[32*8*32]         (32 KB: [group][slice], 128B stride)
//   1048576  Hf    __half[512][512]     (512 KB)  Euler h mirror
//   1572864  Tf    __half[512][512]     (512 KB)  Euler tanh mirror
//   2097152  T2f   __half[512][512]     (512 KB)  P1 relu mirror (deferred P2)
//   2621440  Hf2   __half[512][512]     (512 KB)  LSTM h' mirror (obs rows)
//   4194304  WF    frag-swizzled f16 weights (4.33 MB)
// WF half-offsets: W1 0, W2 262144, Wp1 524288, Wp2 786432, Wg 851968
//   frag layout: idx = ((coltile*KT + ktile)*64 + lane)*8 + e
//   element = W[ktile*32 + (lane>>4)*8 + e][coltile*16 + (lane&15)]

typedef _Float16 f16x8 __attribute__((ext_vector_type(8)));
typedef float    f32x4 __attribute__((ext_vector_type(4)));
typedef unsigned long long u64;

__device__ __forceinline__ float sigm(float x){ return 1.0f/(1.0f + __expf(-x)); }

__device__ __forceinline__ u64 ald(const u64* p){
  return __hip_atomic_load(p, __ATOMIC_RELAXED, __HIP_MEMORY_SCOPE_AGENT);
}
__device__ __forceinline__ void ast(u64* p, u64 v){
  __hip_atomic_store(p, v, __ATOMIC_RELAXED, __HIP_MEMORY_SCOPE_AGENT);
}

union HU { __half h[8]; u64 q[2]; };

__global__ void k_init(int* __restrict__ pos, float* __restrict__ acc,
                       int* __restrict__ flg, uint32_t* __restrict__ hf){
  int i = blockIdx.x*blockDim.x + threadIdx.x;
  if (i < Kn*Bn) pos[i] = -1;
  if (i < 2) acc[i] = 0.0f;
  if (i < 32*8*32) flg[i] = 0;
  if (i < Hn*Hn/2) hf[i] = 0;
}

__global__ void k_scatter(const int* __restrict__ bidx, int* __restrict__ pos){
  int i = blockIdx.x*blockDim.x + threadIdx.x;
  if (i < Kn*En){
    int k = i >> 8;
    int e = i & (En-1);
    pos[(k << 9) | bidx[i]] = e;
  }
}

__global__ void k_cvt_frag(const float* __restrict__ src, __half* __restrict__ dst,
                           int KT, int N, int n){
  int i = blockIdx.x*blockDim.x + threadIdx.x;
  if (i >= n) return;
  int C = i / (KT*512);
  int r = i % (KT*512);
  int T = r >> 9;
  int q = r & 511;
  int l = q >> 3, e = q & 7;
  int srow = T*32 + ((l>>4)<<3) + e;
  int scol = C*16 + (l&15);
  dst[i] = __float2half(src[(size_t)srow*N + scol]);
}

__device__ __forceinline__ f32x4 mv16(const __half* Af, const f16x8* Wr, int lane){
  f32x4 a = {0.f,0.f,0.f,0.f};
  #pragma unroll
  for (int kt=0; kt<16; kt++){
    f16x8 av = *(const f16x8*)(Af + kt*512 + lane*8);
    a = __builtin_amdgcn_mfma_f32_16x16x32_f16(av, Wr[kt], a, 0,0,0);
  }
  return a;
}

__global__ __launch_bounds__(NTH, 1) void k_main(
  const float* __restrict__ X, const float* __restrict__ Mm,
  const int* __restrict__ pos, const __half* __restrict__ WF,
  __half* __restrict__ Hf, __half* __restrict__ Tf,
  __half* __restrict__ T2f, __half* __restrict__ Hf2,
  const float* __restrict__ bi_, const float* __restrict__ bf_,
  const float* __restrict__ bo_, const float* __restrict__ bc_,
  const float* __restrict__ b1_, const float* __restrict__ b2_,
  const float* __restrict__ bp1_, const float* __restrict__ bp2_,
  float* __restrict__ acc, int* __restrict__ flg)
{
  const __half* W1F  = WF;
  const __half* W2F  = WF + 262144;
  const __half* Wp1F = WF + 524288;
  const __half* Wp2F = WF + 786432;
  const __half* WgF  = WF + 851968;

  const int t    = threadIdx.x;
  const int bid  = blockIdx.x;
  const int s    = bid & 7;      // slice = XCD under round-robin (perf-only)
  const int g    = bid >> 3;     // group 0..31
  const int w    = t >> 6;
  const int lane = t & 63;
  int* flgbase = flg + g*8*32;

  __shared__ __align__(16) __half Afrag[16*512];   // 16KB
  __shared__ __align__(16) __half Bfrag[16*512];   // 16KB (deferred T2f staging)
  __shared__ __align__(16) __half Xfrag[4*512];    // 4KB
  __shared__ __align__(16) float  outb[20*256];    // 20KB
  __shared__ float redbuf[8];

  const int row = t >> 4;
  const int q4  = t & 15;
  const int sc  = s*64 + q4*4;
  float Hreg[4] = {0,0,0,0};
  float Creg[4] = {0,0,0,0};
  float vb1[4], vb2[4], vbp1[4], vbi[4], vbf[4], vbo[4], vbc[4];
  #pragma unroll
  for (int i=0;i<4;i++){
    vb1[i]=b1_[sc+i]; vb2[i]=b2_[sc+i]; vbp1[i]=bp1_[sc+i];
    vbi[i]=bi_[sc+i]; vbf[i]=bf_[sc+i]; vbo[i]=bo_[sc+i]; vbc[i]=bc_[sc+i];
  }
  const float vbp2 = bp2_[s*16 + q4];

  // hoist W1/W2/Wp1 wave-slices into registers (R7-proven)
  f16x8 W1r[16], W2r[16], Wp1r[16];
  {
    const size_t cb = (size_t)(s*4 + w)*16*512 + (size_t)lane*8;
    #pragma unroll
    for (int kt=0; kt<16; kt++){
      W1r[kt]  = *(const f16x8*)(W1F  + cb + kt*512);
      W2r[kt]  = *(const f16x8*)(W2F  + cb + kt*512);
      Wp1r[kt] = *(const f16x8*)(Wp1F + cb + kt*512);
    }
  }

  float loss_loc = 0.f, m_loc = 0.f;
  int rnd = 0;
  const int grow = g*16 + row;

#define POLL() do{                                                         \
    if (t < 8){                                                            \
      while (__hip_atomic_load(flgbase + t*32, __ATOMIC_RELAXED,           \
                               __HIP_MEMORY_SCOPE_AGENT) < rnd)            \
        __builtin_amdgcn_s_sleep(1);                                       \
    }                                                                      \
    __syncthreads();                                                       \
  }while(0)

#define PUBLISH() do{                                                      \
    asm volatile("s_waitcnt vmcnt(0)" ::: "memory");                       \
    __syncthreads();                                                       \
    rnd++;                                                                 \
    if (t == 0)                                                            \
      __hip_atomic_store(flgbase + s*32, rnd, __ATOMIC_RELAXED,            \
                         __HIP_MEMORY_SCOPE_AGENT);                        \
  }while(0)

// stage 16 rows x 512 cols from SRC (u64 ald) into A-frag layout at DST
#define STAGE(DST, SRCPTR) do{                                             \
    const int ar = t & 15, ch = t >> 4;                                    \
    const u64* sp = (const u64*)((SRCPTR) + ((size_t)(g*16+ar))*512 + ch*32); \
    u64 v[8];                                                              \
    _Pragma("unroll") for (int i=0;i<8;i++) v[i] = ald(sp+i);              \
    _Pragma("unroll")                                                      \
    for (int kg=0;kg<4;kg++){                                              \
      u64* d = (u64*)((DST) + ch*512 + (ar + 16*kg)*8);                    \
      d[0] = v[2*kg]; d[1] = v[2*kg+1];                                    \
    }                                                                      \
  }while(0)

  for (int k=0; k<Kn; k++){
    const int epos = pos[(k<<9) + grow];

    // ============ P1e: deferred P2+loss (k-1) + Euler step1-W1 ============
    POLL();
    if (k > 0) STAGE(Bfrag, T2f);
    {
      // stage h with per-row select: obs(k-1) rows from Hf2, else Hf
      const int ar = t & 15, ch = t >> 4;
      const __half* hsrc = Hf;
      if (k > 0 && pos[((k-1)<<9) + g*16 + ar] >= 0) hsrc = Hf2;
      const u64* sp = (const u64*)(hsrc + ((size_t)(g*16+ar))*512 + ch*32);
      u64 v[8];
      #pragma unroll
      for (int i=0;i<8;i++) v[i] = ald(sp+i);
      #pragma unroll
      for (int kg=0;kg<4;kg++){
        u64* d = (u64*)(Afrag + ch*512 + (ar + 16*kg)*8);
        d[0] = v[2*kg]; d[1] = v[2*kg+1];
      }
    }
    __syncthreads();
    {
      f32x4 a4 = mv16(Afrag, W1r, lane);
      float* o = outb + w*256 + ((lane>>4)*4)*16 + (lane&15);
      o[0]=a4[0]; o[16]=a4[1]; o[32]=a4[2]; o[48]=a4[3];
    }
    if (k > 0){
      // deferred P2 for event k-1: coltile s of Wp2, wave w ktiles w*4..+3
      const __half* wb = Wp2F + (size_t)s*16*512;
      f32x4 a4 = {0,0,0,0};
      #pragma unroll
      for (int kt2=0; kt2<4; kt2++){
        const int kt = w*4 + kt2;
        f16x8 a = *(const f16x8*)(Bfrag + kt*512 + lane*8);
        f16x8 b = *(const f16x8*)(wb + kt*512 + lane*8);
        a4 = __builtin_amdgcn_mfma_f32_16x16x32_f16(a, b, a4, 0,0,0);
      }
      float* o = outb + (16+w)*256 + ((lane>>4)*4)*16 + (lane&15);
      o[0]=a4[0]; o[16]=a4[1]; o[32]=a4[2]; o[48]=a4[3];
    }
    __syncthreads();
    {
      const float* o = outb + (q4>>2)*256 + row*16 + (q4&3)*4;
      HU u;
      u.h[0]=__float2half(tanhf(o[0]+vb1[0])); u.h[1]=__float2half(tanhf(o[1]+vb1[1]));
      u.h[2]=__float2half(tanhf(o[2]+vb1[2])); u.h[3]=__float2half(tanhf(o[3]+vb1[3]));
      ast((u64*)(Tf + (size_t)grow*512 + sc), u.q[0]);
    }
    PUBLISH();
    if (k > 0){   // loss for event k-1 in barrier shadow (block-local)
      const int ep = pos[((k-1)<<9) + g*16 + row];
      if (ep >= 0){
        float p = outb[16*256 + row*16+q4] + outb[17*256 + row*16+q4]
                + outb[18*256 + row*16+q4] + outb[19*256 + row*16+q4] + vbp2;
        const size_t xo = ((size_t)((k-1)*En+ep))*Dn + s*16 + q4;
        float mo = Mm[xo];
        loss_loc += fabsf(X[xo] - p)*mo;
        m_loc    += mo;
      }
    }

    // ============ P2e: Euler step1-W2 (h += dt*(T@W2+b2)) ============
    POLL();
    STAGE(Afrag, Tf);
    __syncthreads();
    {
      f32x4 a4 = mv16(Afrag, W2r, lane);
      float* o = outb + w*256 + ((lane>>4)*4)*16 + (lane&15);
      o[0]=a4[0]; o[16]=a4[1]; o[32]=a4[2]; o[48]=a4[3];
    }
    __syncthreads();
    {
      const float* o = outb + (q4>>2)*256 + row*16 + (q4&3)*4;
      HU u;
      Hreg[0] += DT_C*(o[0]+vb2[0]); Hreg[1] += DT_C*(o[1]+vb2[1]);
      Hreg[2] += DT_C*(o[2]+vb2[2]); Hreg[3] += DT_C*(o[3]+vb2[3]);
      u.h[0]=__float2half(Hreg[0]); u.h[1]=__float2half(Hreg[1]);
      u.h[2]=__float2half(Hreg[2]); u.h[3]=__float2half(Hreg[3]);
      ast((u64*)(Hf + (size_t)grow*512 + sc), u.q[0]);
    }
    PUBLISH();

    // ============ P3e: Euler step2-W1 ============
    POLL();
    STAGE(Afrag, Hf);
    __syncthreads();
    {
      f32x4 a4 = mv16(Afrag, W1r, lane);
      float* o = outb + w*256 + ((lane>>4)*4)*16 + (lane&15);
      o[0]=a4[0]; o[16]=a4[1]; o[32]=a4[2]; o[48]=a4[3];
    }
    __syncthreads();
    {
      const float* o = outb + (q4>>2)*256 + row*16 + (q4&3)*4;
      HU u;
      u.h[0]=__float2half(tanhf(o[0]+vb1[0])); u.h[1]=__float2half(tanhf(o[1]+vb1[1]));
      u.h[2]=__float2half(tanhf(o[2]+vb1[2])); u.h[3]=__float2half(tanhf(o[3]+vb1[3]));
      ast((u64*)(Tf + (size_t)grow*512 + sc), u.q[0]);
    }
    PUBLISH();

    // ============ P4e: Euler step2-W2 ============
    POLL();
    STAGE(Afrag, Tf);
    __syncthreads();
    {
      f32x4 a4 = mv16(Afrag, W2r, lane);
      float* o = outb + w*256 + ((lane>>4)*4)*16 + (lane&15);
      o[0]=a4[0]; o[16]=a4[1]; o[32]=a4[2]; o[48]=a4[3];
    }
    __syncthreads();
    {
      const float* o = outb + (q4>>2)*256 + row*16 + (q4&3)*4;
      HU u;
      Hreg[0] += DT_C*(o[0]+vb2[0]); Hreg[1] += DT_C*(o[1]+vb2[1]);
      Hreg[2] += DT_C*(o[2]+vb2[2]); Hreg[3] += DT_C*(o[3]+vb2[3]);
      u.h[0]=__float2half(Hreg[0]); u.h[1]=__float2half(Hreg[1]);
      u.h[2]=__float2half(Hreg[2]); u.h[3]=__float2half(Hreg[3]);
      ast((u64*)(Hf + (size_t)grow*512 + sc), u.q[0]);
    }
    PUBLISH();

    // ====== P56: P1 -> T2f, gates, LSTM -> Hf2 (one barrier) ======
    POLL();
    STAGE(Afrag, Hf);
    if (t < 64){
      const int ar = t & 15, ch = t >> 4;
      const int e = pos[(k<<9) + g*16 + ar];
      float xv[32];
      if (e >= 0){
        const float4* xp = (const float4*)(X + ((size_t)(k*En+e))*Dn + ch*32);
        #pragma unroll
        for (int i=0;i<8;i++){
          float4 f = xp[i];
          xv[4*i]=f.x; xv[4*i+1]=f.y; xv[4*i+2]=f.z; xv[4*i+3]=f.w;
        }
      } else {
        #pragma unroll
        for (int i=0;i<32;i++) xv[i]=0.f;
      }
      #pragma unroll
      for (int kg=0;kg<4;kg++){
        HU u;
        #pragma unroll
        for (int e8=0;e8<8;e8++) u.h[e8] = __float2half(xv[kg*8+e8]);
        u64* d = (u64*)(Xfrag + ch*512 + (ar + 16*kg)*8);
        d[0] = u.q[0]; d[1] = u.q[1];
      }
    }
    __syncthreads();
    {   // P1 -> outb 16+w
      f32x4 a4 = mv16(Afrag, Wp1r, lane);
      float* o = outb + (16+w)*256 + ((lane>>4)*4)*16 + (lane&15);
      o[0]=a4[0]; o[16]=a4[1]; o[32]=a4[2]; o[48]=a4[3];
    }
    // gates: Cg = w*32 + s*4 + i -> outb slots w*4+i
    #pragma unroll 1
    for (int i=0;i<4;i++){
      const int Cg = w*32 + s*4 + i;
      const __half* wb = WgF + (size_t)Cg*20*512;
      f32x4 a4 = {0,0,0,0};
      #pragma unroll 4
      for (int kt=0; kt<4; kt++){
        f16x8 a = *(const f16x8*)(Xfrag + kt*512 + lane*8);
        f16x8 b = *(const f16x8*)(wb + kt*512 + lane*8);
        a4 = __builtin_amdgcn_mfma_f32_16x16x32_f16(a, b, a4, 0,0,0);
      }
      #pragma unroll 4
      for (int kt=4; kt<20; kt++){
        f16x8 a = *(const f16x8*)(Afrag + (kt-4)*512 + lane*8);
        f16x8 b = *(const f16x8*)(wb + kt*512 + lane*8);
        a4 = __builtin_amdgcn_mfma_f32_16x16x32_f16(a, b, a4, 0,0,0);
      }
      float* o = outb + (w*4+i)*256 + ((lane>>4)*4)*16 + (lane&15);
      o[0]=a4[0]; o[16]=a4[1]; o[32]=a4[2]; o[48]=a4[3];
    }
    __syncthreads();
    {   // relu(P1) -> T2f (read by deferred P2 next event)
      const float* o = outb + (16+(q4>>2))*256 + row*16 + (q4&3)*4;
      HU u;
      u.h[0]=__float2half(fmaxf(o[0]+vbp1[0],0.f));
      u.h[1]=__float2half(fmaxf(o[1]+vbp1[1],0.f));
      u.h[2]=__float2half(fmaxf(o[2]+vbp1[2],0.f));
      u.h[3]=__float2half(fmaxf(o[3]+vbp1[3],0.f));
      ast((u64*)(T2f + (size_t)grow*512 + sc), u.q[0]);
    }
    if (epos >= 0){   // LSTM update -> Hf2 (obs rows only; Hreg/Creg canonical)
      const int sub = q4 >> 2, off = row*16 + (q4&3)*4;
      const float4 pi = *(const float4*)(outb + (0*4+sub)*256 + off);
      const float4 pf = *(const float4*)(outb + (1*4+sub)*256 + off);
      const float4 po = *(const float4*)(outb + (2*4+sub)*256 + off);
      const float4 pc = *(const float4*)(outb + (3*4+sub)*256 + off);
      HU hu;
      const float gi[4]={pi.x,pi.y,pi.z,pi.w}, gf[4]={pf.x,pf.y,pf.z,pf.w};
      const float go[4]={po.x,po.y,po.z,po.w}, gc[4]={pc.x,pc.y,pc.z,pc.w};
      #pragma unroll
      for (int i=0;i<4;i++){
        float ig = sigm(gi[i] + vbi[i]);
        float fg = sigm(gf[i] + vbf[i]);
        float og = sigm(go[i] + vbo[i]);
        float ct = tanhf(gc[i] + vbc[i]);
        Creg[i] = fg*Creg[i] + ig*ct;
        Hreg[i] = og*tanhf(Creg[i]);
        hu.h[i] = __float2half(Hreg[i]);
      }
      ast((u64*)(Hf2 + (size_t)grow*512 + sc), hu.q[0]);
    }
    PUBLISH();
  }

  // ===== epilogue: deferred P2+loss for event Kn-1 =====
  POLL();
  STAGE(Bfrag, T2f);
  __syncthreads();
  {
    const __half* wb = Wp2F + (size_t)s*16*512;
    f32x4 a4 = {0,0,0,0};
    #pragma unroll
    for (int kt2=0; kt2<4; kt2++){
      const int kt = w*4 + kt2;
      f16x8 a = *(const f16x8*)(Bfrag + kt*512 + lane*8);
      f16x8 b = *(const f16x8*)(wb + kt*512 + lane*8);
      a4 = __builtin_amdgcn_mfma_f32_16x16x32_f16(a, b, a4, 0,0,0);
    }
    float* o = outb + (16+w)*256 + ((lane>>4)*4)*16 + (lane&15);
    o[0]=a4[0]; o[16]=a4[1]; o[32]=a4[2]; o[48]=a4[3];
  }
  __syncthreads();
  {
    const int ep = pos[((Kn-1)<<9) + g*16 + row];
    if (ep >= 0){
      float p = outb[16*256 + row*16+q4] + outb[17*256 + row*16+q4]
              + outb[18*256 + row*16+q4] + outb[19*256 + row*16+q4] + vbp2;
      const size_t xo = ((size_t)((Kn-1)*En+ep))*Dn + s*16 + q4;
      float mo = Mm[xo];
      loss_loc += fabsf(X[xo] - p)*mo;
      m_loc    += mo;
    }
  }

  // block reduction -> global atomics
  #pragma unroll
  for (int off=32; off>0; off>>=1){
    loss_loc += __shfl_down(loss_loc, off);
    m_loc    += __shfl_down(m_loc, off);
  }
  if (lane == 0){ redbuf[w] = loss_loc; redbuf[4+w] = m_loc; }
  __syncthreads();
  if (t == 0){
    atomicAdd(acc+0, redbuf[0]+redbuf[1]+redbuf[2]+redbuf[3]);
    atomicAdd(acc+1, redbuf[4]+redbuf[5]+redbuf[6]+redbuf[7]);
  }
#undef POLL
#undef PUBLISH
#undef STAGE
}

__global__ void k_fin(const float* __restrict__ acc, float* __restrict__ out){
  if (threadIdx.x == 0){
    out[0] = acc[0];
    out[1] = acc[0]/acc[1];
  }
}

extern "C" void kernel_launch(void* const* d_in, const int* in_sizes, int n_in,
                              void* d_out, int out_size, void* d_ws, size_t ws_size,
                              hipStream_t stream)
{
  const float* X   = (const float*)d_in[0];
  const float* Mm  = (const float*)d_in[1];
  const int*  bidx = (const int*)d_in[2];
  const float* Wi  = (const float*)d_in[4];
  const float* bi  = (const float*)d_in[5];
  const float* Wf  = (const float*)d_in[6];
  const float* bff = (const float*)d_in[7];
  const float* Wo  = (const float*)d_in[8];
  const float* bo  = (const float*)d_in[9];
  const float* Wc  = (const float*)d_in[10];
  const float* bc  = (const float*)d_in[11];
  const float* W1  = (const float*)d_in[12];
  const float* b1  = (const float*)d_in[13];
  const float* W2  = (const float*)d_in[14];
  const float* b2  = (const float*)d_in[15];
  const float* Wp1 = (const float*)d_in[16];
  const float* bp1 = (const float*)d_in[17];
  const float* Wp2 = (const float*)d_in[18];
  const float* bp2 = (const float*)d_in[19];

  char* ws = (char*)d_ws;
  int*    pos = (int*)ws;
  float*  acc = (float*)(ws + 131072);
  int*    flg = (int*)(ws + 196608);
  __half* Hf  = (__half*)(ws + 1048576);
  __half* Tf  = (__half*)(ws + 1572864);
  __half* T2f = (__half*)(ws + 2097152);
  __half* Hf2 = (__half*)(ws + 2621440);
  __half* WF  = (__half*)(ws + 4194304);

  k_init   <<<512, 256, 0, stream>>>(pos, acc, flg, (uint32_t*)Hf);
  k_scatter<<<(Kn*En + 255)/256, 256, 0, stream>>>(bidx, pos);

  k_cvt_frag<<<(262144+255)/256, 256, 0, stream>>>(W1,  WF,          16, 512, 262144);
  k_cvt_frag<<<(262144+255)/256, 256, 0, stream>>>(W2,  WF + 262144, 16, 512, 262144);
  k_cvt_frag<<<(262144+255)/256, 256, 0, stream>>>(Wp1, WF + 524288, 16, 512, 262144);
  k_cvt_frag<<<(65536 +255)/256, 256, 0, stream>>>(Wp2, WF + 786432, 16, 128, 65536);
  k_cvt_frag<<<(327680+255)/256, 256, 0, stream>>>(Wi,  WF + 851968,            20, 512, 327680);
  k_cvt_frag<<<(327680+255)/256, 256, 0, stream>>>(Wf,  WF + 851968 + 327680,   20, 512, 327680);
  k_cvt_frag<<<(327680+255)/256, 256, 0, stream>>>(Wo,  WF + 851968 + 655360,   20, 512, 327680);
  k_cvt_frag<<<(327680+255)/256, 256, 0, stream>>>(Wc,  WF + 851968 + 983040,   20, 512, 327680);

  k_main<<<NBLK, NTH, 0, stream>>>(X, Mm, pos, WF, Hf, Tf, T2f, Hf2,
                                   bi, bff, bo, bc, b1, b2, bp1, bp2, acc, flg);
  k_fin<<<1, 64, 0, stream>>>(acc, (float*)d_out);
}